// Round 6
// baseline (152.674 us; speedup 1.0000x reference)
//
#include <hip/hip_runtime.h>
#include <math.h>

#define NHF 128
#define NRBF 50
#define LAYERS 3
#define CUTOFF_F 5.0f
#define STEP_F (CUTOFF_F/49.0f)
#define LOG2_F 0.6931471805599453f
#define PI_F 3.14159265358979323846f
#define TBL 2048
#define TROWS (TBL+1)
#define TINV ((float)TBL / CUTOFF_F)

typedef __attribute__((ext_vector_type(8))) __bf16 bf16x8;
typedef __attribute__((ext_vector_type(4))) float f32x4;
typedef _Float16 f16x2 __attribute__((ext_vector_type(2)));

static __device__ __forceinline__ unsigned short f2bf(float f){
    unsigned u = __builtin_bit_cast(unsigned, f);
    u += 0x7fff + ((u >> 16) & 1);          // RNE
    return (unsigned short)(u >> 16);
}
static __device__ __forceinline__ unsigned packbf(float lo, float hi){
    unsigned short a = __builtin_bit_cast(unsigned short, (__bf16)lo);
    unsigned short b = __builtin_bit_cast(unsigned short, (__bf16)hi);
    return (unsigned)a | ((unsigned)b << 16);
}
static __device__ __forceinline__ unsigned packh(float lo, float hi){
    auto h = __builtin_amdgcn_cvt_pkrtz(lo, hi);   // __fp16 ext_vector(2)
    return __builtin_bit_cast(unsigned, h);
}
static __device__ __forceinline__ float sspf(float x){
    return fmaxf(x, 0.0f) + log1pf(expf(-fabsf(x))) - LOG2_F;
}
// swizzled word index for LDS tiles [32 rows][64 words]
static __device__ __forceinline__ int swz(int row, int wc){
    return row * 64 + (wc ^ ((row & 7) << 2));
}

// ---- pack 9 weight matrices [128][128] f32 -> bf16 MFMA B-fragment order ----
__global__ __launch_bounds__(256) void k_pack(const float* __restrict__ in2f_W, const float* __restrict__ o_W1,
                                              const float* __restrict__ o_W2, uint4* __restrict__ Wp){
    int tid = blockIdx.x * 256 + threadIdx.x;      // 9*2048 total
    if (tid >= 9 * 2048) return;
    int g = tid >> 11;
    int rem = tid & 2047;
    int s = rem >> 9;
    int f = (rem >> 6) & 7;
    int l = rem & 63;
    int layer = g / 3, type = g % 3;
    const float* src = (type == 0 ? in2f_W : (type == 1 ? o_W1 : o_W2)) + (size_t)layer * NHF * NHF;
    int row0 = s * 32 + ((l >> 4) << 3);
    int col  = (f << 4) + (l & 15);
    unsigned p0, p1, p2, p3;
    p0 = (unsigned)f2bf(src[(row0+0)*NHF + col]) | ((unsigned)f2bf(src[(row0+1)*NHF + col]) << 16);
    p1 = (unsigned)f2bf(src[(row0+2)*NHF + col]) | ((unsigned)f2bf(src[(row0+3)*NHF + col]) << 16);
    p2 = (unsigned)f2bf(src[(row0+4)*NHF + col]) | ((unsigned)f2bf(src[(row0+5)*NHF + col]) << 16);
    p3 = (unsigned)f2bf(src[(row0+6)*NHF + col]) | ((unsigned)f2bf(src[(row0+7)*NHF + col]) << 16);
    Wp[tid] = make_uint4(p0, p1, p2, p3);
}

// ---- fused filter table (f16): T[l][t][c] = f16( (ssp(rbf(r_t)@W1+b1)@W2+b2) * dc(r_t) ) ----
// grid (ceil(TROWS/8), LAYERS); 256 threads = 2 groups of 128, 4 rows per group
__global__ __launch_bounds__(256) void k_table(const float* __restrict__ W1, const float* __restrict__ b1,
                                               const float* __restrict__ W2, const float* __restrict__ b2,
                                               unsigned short* __restrict__ Th){
    __shared__ float rbfL[2][4][52];
    __shared__ float hidL[2][4][128];
    int l = blockIdx.y;
    int tid = threadIdx.x;
    int g = tid >> 7, c = tid & 127;
    const float* W1l = W1 + (size_t)l * NRBF * NHF;
    const float* W2l = W2 + (size_t)l * NHF * NHF;
    int t0 = blockIdx.x * 8 + g * 4;
    const float coeff = -0.5f / (STEP_F * STEP_F);
    const float dr = CUTOFF_F / (float)TBL;
    if (c < NRBF){
        float off = c * STEP_F;
        #pragma unroll
        for (int i = 0; i < 4; i++){
            int t = t0 + i; if (t > TBL) t = TBL;
            float d = t * dr - off;
            rbfL[g][i][c] = expf(coeff * d * d);
        }
    }
    __syncthreads();
    float acc[4];
    float bc = b1[l * NHF + c];
    #pragma unroll
    for (int i = 0; i < 4; i++) acc[i] = bc;
    for (int j = 0; j < NRBF; j++){
        float wv = W1l[j * NHF + c];
        #pragma unroll
        for (int i = 0; i < 4; i++) acc[i] = fmaf(rbfL[g][i][j], wv, acc[i]);
    }
    #pragma unroll
    for (int i = 0; i < 4; i++) hidL[g][i][c] = sspf(acc[i]);
    __syncthreads();
    float b2c = b2[l * NHF + c];
    #pragma unroll
    for (int i = 0; i < 4; i++) acc[i] = b2c;
    for (int j = 0; j < NHF; j++){
        float wv = W2l[j * NHF + c];
        #pragma unroll
        for (int i = 0; i < 4; i++) acc[i] = fmaf(hidL[g][i][j], wv, acc[i]);
    }
    #pragma unroll
    for (int i = 0; i < 4; i++){
        int t = t0 + i; if (t > TBL) t = TBL;
        float r = t * dr;
        float dc = (t >= TBL) ? 0.0f : 0.5f * (cosf(r * (PI_F / CUTOFF_F)) + 1.0f);
        float v = acc[i] * dc;
        Th[((size_t)l * TROWS + t) * NHF + c] = __builtin_bit_cast(unsigned short, (_Float16)v);
    }
}

// ---- MFMA helpers ----
static __device__ __forceinline__ bf16x8 ldA(const unsigned* A_u, int rfbase, int ks, int l){
    int row = rfbase + (l & 15);
    int wc = ks * 16 + ((l >> 4) << 2);
    uint4 v = *reinterpret_cast<const uint4*>(&A_u[row * 64 + (wc ^ ((row & 7) << 2))]);
    return __builtin_bit_cast(bf16x8, v);
}
static __device__ __forceinline__ bf16x8 ldB(const uint4* __restrict__ Wp, int g, int ks, int cfg, int l){
    uint4 v = Wp[(((g << 2) + ks) * 8 + cfg) * 64 + l];
    return __builtin_bit_cast(bf16x8, v);
}

// EPI 0: D -> dst.  EPI 1: ssp(D + bias) -> dst.  EPI 2: hreg += D + bias; -> dst
// WFMT 0: bf16 pairs, 1: f16 pairs
template<int EPI, int WFMT>
static __device__ __forceinline__ void gemm_phase(const uint4* __restrict__ Wp, int g,
                                                  const unsigned* A_u, unsigned* D_u,
                                                  float hreg[2][2][4], const float* __restrict__ bias,
                                                  int w, int l){
    f32x4 acc00 = {0,0,0,0}, acc01 = {0,0,0,0}, acc10 = {0,0,0,0}, acc11 = {0,0,0,0};
    #pragma unroll
    for (int ks = 0; ks < 4; ks++){
        bf16x8 va0 = ldA(A_u, 0, ks, l);
        bf16x8 va1 = ldA(A_u, 16, ks, l);
        bf16x8 vb0 = ldB(Wp, g, ks, w * 2 + 0, l);
        bf16x8 vb1 = ldB(Wp, g, ks, w * 2 + 1, l);
        acc00 = __builtin_amdgcn_mfma_f32_16x16x32_bf16(va0, vb0, acc00, 0, 0, 0);
        acc01 = __builtin_amdgcn_mfma_f32_16x16x32_bf16(va0, vb1, acc01, 0, 0, 0);
        acc10 = __builtin_amdgcn_mfma_f32_16x16x32_bf16(va1, vb0, acc10, 0, 0, 0);
        acc11 = __builtin_amdgcn_mfma_f32_16x16x32_bf16(va1, vb1, acc11, 0, 0, 0);
    }
    #pragma unroll
    for (int rf = 0; rf < 2; rf++){
        #pragma unroll
        for (int cf = 0; cf < 2; cf++){
            f32x4 a = (rf == 0) ? (cf == 0 ? acc00 : acc01) : (cf == 0 ? acc10 : acc11);
            int colb = w * 32 + cf * 16;
            float bv = (EPI >= 1) ? bias[colb + (l & 15)] : 0.0f;
            #pragma unroll
            for (int r = 0; r < 4; r++){
                float v = a[r] + bv;
                if (EPI == 1) v = sspf(v);
                if (EPI == 2){ v += hreg[rf][cf][r]; hreg[rf][cf][r] = v; }
                float pv = __shfl_xor(v, 1);
                if (!(l & 1)){
                    int row = rf * 16 + ((l >> 4) << 2) + r;
                    int wc  = (colb >> 1) + ((l & 15) >> 1);
                    D_u[swz(row, wc)] = WFMT ? packh(v, pv) : packbf(v, pv);
                }
            }
        }
    }
}

// ---- mega kernel: one block = one molecule, all 3 layers + readout ----
__global__ __launch_bounds__(256, 4) void k_mega(const int* __restrict__ z, const float* __restrict__ coord,
                                                 const float* __restrict__ emask, const float* __restrict__ amask,
                                                 const float* __restrict__ emb,
                                                 const uint4* __restrict__ Wp,
                                                 const float* __restrict__ o_b1, const float* __restrict__ o_b2,
                                                 const unsigned* __restrict__ Tb,
                                                 const float* __restrict__ dW1, const float* __restrict__ db1,
                                                 const float* __restrict__ dW2, const float* __restrict__ db2,
                                                 const int* __restrict__ ridx, const float* __restrict__ rsign,
                                                 float* __restrict__ pred, int nn){
    __shared__ __align__(16) unsigned hbf[32 * 64];     // bf16 h (A input)
    __shared__ __align__(16) unsigned xfb[32 * 64];     // xf (f16), then t (bf16)
    __shared__ __align__(16) unsigned mbu[32 * 64];     // edge messages m (bf16)
    __shared__ int      pkE[32 * 32];                   // col | (t<<5)
    __shared__ int      cntL[32];
    __shared__ unsigned maskL[32];
    __shared__ float    cxyz[96];
    __shared__ float    amL[32];
    __shared__ float    hsb[NHF];

    int mol = blockIdx.x;
    int tid = threadIdx.x;
    int w = tid >> 6, l = tid & 63;
    int molA = mol * nn;
    int km = nn - 1;
    int ne = nn * km;

    // ---- cooperative staging ----
    if (tid < 32) maskL[tid] = 0u;
    if (tid < 3 * nn) cxyz[tid] = coord[(size_t)molA * 3 + tid];
    if (tid < 32)     amL[tid] = (tid < nn) ? amask[molA + tid] : 0.0f;
    for (int i = tid; i < (32 - nn) * 64; i += 256){    // zero mbu pad rows
        int row = nn + (i >> 6);
        mbu[swz(row, i & 63)] = 0u;
    }
    __syncthreads();
    for (int e = tid; e < ne; e += 256){
        if (emask[(size_t)molA * km + e] != 0.0f){
            int a = e / km, k = e - a * km;
            atomicOr(&maskL[a], 1u << k);
        }
    }

    // ---- h init: registers (C-fragment layout) + bf16 LDS copy ----
    float hreg[2][2][4];
    #pragma unroll
    for (int rf = 0; rf < 2; rf++){
        #pragma unroll
        for (int cf = 0; cf < 2; cf++){
            int colb = w * 32 + cf * 16;
            #pragma unroll
            for (int r = 0; r < 4; r++){
                int row = rf * 16 + ((l >> 4) << 2) + r;
                float v = 0.0f;
                if (row < nn) v = emb[(size_t)z[molA + row] * NHF + colb + (l & 15)];
                hreg[rf][cf][r] = v;
                float pv = __shfl_xor(v, 1);
                if (!(l & 1)){
                    int wc = (colb >> 1) + ((l & 15) >> 1);
                    hbf[swz(row, wc)] = packbf(v, pv);
                }
            }
        }
    }
    __syncthreads();

    // ---- per-atom active-edge lists, padded to multiple of 8 with zero-row edges ----
    if (tid < nn){
        int ai = tid;
        unsigned msk = maskL[ai];
        float ax = cxyz[ai*3], ay = cxyz[ai*3+1], az = cxyz[ai*3+2];
        int cnt = 0;
        for (int k = 0; k < km; k++){
            int nb = k + (k >= ai ? 1 : 0);
            float dx = ax - cxyz[nb*3], dy = ay - cxyz[nb*3+1], dz = az - cxyz[nb*3+2];
            float r = sqrtf(dx*dx + dy*dy + dz*dz);
            int t = (int)(r * TINV + 0.5f);
            if (((msk >> k) & 1u) && t < TBL){
                pkE[ai * 32 + cnt] = nb | (t << 5);
                cnt++;
            }
        }
        int cp = (cnt + 7) & ~7;
        for (int k = cnt; k < cp; k++) pkE[ai * 32 + k] = (TBL << 5);  // T row TBL = zeros
        cntL[ai] = cp;
    }
    __syncthreads();

    for (int L = 0; L < LAYERS; L++){
        // in2f: xf = h @ W (no bias) -> f16 pairs
        gemm_phase<0, 1>(Wp, L * 3 + 0, hbf, xfb, hreg, o_b1, w, l);
        __syncthreads();
        // edge messages: m[a] = sum_k xf[col_k] * T[t_k]  (lane owns channels 2l,2l+1)
        const unsigned* Tl = Tb + (size_t)L * TROWS * 64;
        for (int a = w; a < nn; a += 4){
            int cnt = cntL[a];
            const int* pe = &pkE[a * 32];
            f16x2 acc; acc[0] = (_Float16)0; acc[1] = (_Float16)0;
            for (int k = 0; k < cnt; k += 8){
                #pragma unroll
                for (int j = 0; j < 8; j++){
                    int p = pe[k + j];
                    unsigned tw = Tl[((p >> 5) << 6) + l];
                    unsigned xw = xfb[swz(p & 31, l)];
                    f16x2 tv = __builtin_bit_cast(f16x2, tw);
                    f16x2 xv = __builtin_bit_cast(f16x2, xw);
                    acc = tv * xv + acc;
                }
            }
            mbu[swz(a, l)] = packbf((float)acc[0], (float)acc[1]);
        }
        __syncthreads();
        // o1: t = ssp(m @ W + b1) -> bf16
        gemm_phase<1, 0>(Wp, L * 3 + 1, mbu, xfb, hreg, o_b1 + L * NHF, w, l);
        __syncthreads();
        // o2: h(reg) += t @ W + b2 ; refresh hbf
        gemm_phase<2, 0>(Wp, L * 3 + 2, xfb, hbf, hreg, o_b2 + L * NHF, w, l);
        __syncthreads();
    }

    // ---- readout: molecule sum (registers) + decoder + scatter ----
    #pragma unroll
    for (int cf = 0; cf < 2; cf++){
        float s = 0.0f;
        #pragma unroll
        for (int rf = 0; rf < 2; rf++){
            #pragma unroll
            for (int r = 0; r < 4; r++){
                int row = rf * 16 + ((l >> 4) << 2) + r;
                s = fmaf(hreg[rf][cf][r], amL[row], s);
            }
        }
        s += __shfl_xor(s, 16);
        s += __shfl_xor(s, 32);
        if (l < 16) hsb[w * 32 + cf * 16 + l] = s;
    }
    __syncthreads();
    // decoder: 256 threads = 64 outputs x 4 c-partitions, reduce in LDS (reuse pkE)
    {
        float* red = (float*)pkE;
        int o = tid & 63, part = tid >> 6;
        float u = 0.0f;
        #pragma unroll 8
        for (int c = part * 32; c < part * 32 + 32; c++)
            u = fmaf(hsb[c], dW1[c * 64 + o], u);
        red[part * 64 + o] = u;
    }
    __syncthreads();
    if (tid < 64){
        float u = ((float*)pkE)[tid] + ((float*)pkE)[64 + tid] + ((float*)pkE)[128 + tid]
                + ((float*)pkE)[192 + tid] + db1[tid];
        float p = sspf(u) * dW2[tid];
        #pragma unroll
        for (int o = 32; o > 0; o >>= 1) p += __shfl_down(p, o);
        if (tid == 0) atomicAdd(&pred[ridx[mol]], (p + db2[0]) * rsign[mol]);
    }
}

extern "C" void kernel_launch(void* const* d_in, const int* in_sizes, int n_in,
                              void* d_out, int out_size, void* d_ws, size_t ws_size,
                              hipStream_t stream){
    const int*   z      = (const int*)  d_in[0];
    const float* coord  = (const float*)d_in[1];
    const float* amask  = (const float*)d_in[3];
    const float* emask  = (const float*)d_in[4];
    const int*   ridx   = (const int*)  d_in[5];
    const float* rsign  = (const float*)d_in[6];
    const float* emb    = (const float*)d_in[7];
    const float* in2f_W = (const float*)d_in[10];
    const float* f_W1   = (const float*)d_in[11];
    const float* f_b1   = (const float*)d_in[12];
    const float* f_W2   = (const float*)d_in[13];
    const float* f_b2   = (const float*)d_in[14];
    const float* o_W1   = (const float*)d_in[15];
    const float* o_b1   = (const float*)d_in[16];
    const float* o_W2   = (const float*)d_in[17];
    const float* o_b2   = (const float*)d_in[18];
    const float* dW1    = (const float*)d_in[19];
    const float* db1    = (const float*)d_in[20];
    const float* dW2    = (const float*)d_in[21];
    const float* db2    = (const float*)d_in[22];

    const int N  = in_sizes[0];
    const int B  = in_sizes[5];
    const int nn = N / B;
    (void)n_in; (void)ws_size;

    // workspace carve
    uint4*    Wp = (uint4*)d_ws;                                   // 9*2048*16 B
    unsigned* Tb = (unsigned*)((char*)d_ws + 9 * 2048 * 16);       // LAYERS*TROWS*64 words (f16 pairs)

    (void)hipMemsetAsync(d_out, 0, (size_t)out_size * sizeof(float), stream);
    k_pack <<<72, 256, 0, stream>>>(in2f_W, o_W1, o_W2, Wp);
    k_table<<<dim3((TROWS + 7) / 8, LAYERS), 256, 0, stream>>>(f_W1, f_b1, f_W2, f_b2,
                                                               (unsigned short*)Tb);
    k_mega <<<B, 256, 0, stream>>>(z, coord, emask, amask, emb, Wp, o_b1, o_b2, Tb,
                                   dW1, db1, dW2, db2, ridx, rsign, (float*)d_out, nn);
}

// Round 7
// 105.504 us; speedup vs baseline: 1.4471x; 1.4471x over previous
//
#include <hip/hip_runtime.h>
#include <math.h>

#define NHF 128
#define NRBF 50
#define LAYERS 3
#define CUTOFF_F 5.0f
#define STEP_F (CUTOFF_F/49.0f)
#define LOG2_F 0.6931471805599453f
#define PI_F 3.14159265358979323846f
#define TBL 2048
#define TROWS (TBL+1)
#define TINV ((float)TBL / CUTOFF_F)

typedef __attribute__((ext_vector_type(8))) _Float16 fp16x8;
typedef __attribute__((ext_vector_type(4))) float f32x4;
typedef _Float16 f16x2 __attribute__((ext_vector_type(2)));

static __device__ __forceinline__ unsigned short f2h(float f){
    return __builtin_bit_cast(unsigned short, (_Float16)f);   // RNE
}
static __device__ __forceinline__ unsigned packh(float lo, float hi){
    auto h = __builtin_amdgcn_cvt_pkrtz(lo, hi);   // __fp16 ext_vector(2)
    return __builtin_bit_cast(unsigned, h);
}
static __device__ __forceinline__ float sspf(float x){
    return fmaxf(x, 0.0f) + log1pf(expf(-fabsf(x))) - LOG2_F;
}
static __device__ __forceinline__ float4 ld4(const float* p){ return *reinterpret_cast<const float4*>(p); }

// ---- pack 9 weight matrices [128][128] f32 -> f16 MFMA fragment order ----
// frag (g, ks, cf): lane l, elem j = W[ks*32 + (l>>4)*8 + j][cf*16 + (l&15)]
__global__ __launch_bounds__(256) void k_pack(const float* __restrict__ in2f_W, const float* __restrict__ o_W1,
                                              const float* __restrict__ o_W2, uint4* __restrict__ Wp){
    int tid = blockIdx.x * 256 + threadIdx.x;      // 9*2048 total
    if (tid >= 9 * 2048) return;
    int g = tid >> 11;
    int rem = tid & 2047;
    int s = rem >> 9;
    int f = (rem >> 6) & 7;
    int l = rem & 63;
    int layer = g / 3, type = g % 3;
    const float* src = (type == 0 ? in2f_W : (type == 1 ? o_W1 : o_W2)) + (size_t)layer * NHF * NHF;
    int row0 = s * 32 + ((l >> 4) << 3);
    int col  = (f << 4) + (l & 15);
    unsigned p0, p1, p2, p3;
    p0 = (unsigned)f2h(src[(row0+0)*NHF + col]) | ((unsigned)f2h(src[(row0+1)*NHF + col]) << 16);
    p1 = (unsigned)f2h(src[(row0+2)*NHF + col]) | ((unsigned)f2h(src[(row0+3)*NHF + col]) << 16);
    p2 = (unsigned)f2h(src[(row0+4)*NHF + col]) | ((unsigned)f2h(src[(row0+5)*NHF + col]) << 16);
    p3 = (unsigned)f2h(src[(row0+6)*NHF + col]) | ((unsigned)f2h(src[(row0+7)*NHF + col]) << 16);
    Wp[tid] = make_uint4(p0, p1, p2, p3);
}

// ---- fused filter table (f16): T[l][t][c] = f16( (ssp(rbf(r_t)@W1+b1)@W2+b2) * dc(r_t) ) ----
__global__ __launch_bounds__(256) void k_table(const float* __restrict__ W1, const float* __restrict__ b1,
                                               const float* __restrict__ W2, const float* __restrict__ b2,
                                               unsigned short* __restrict__ Th){
    __shared__ float rbfL[2][4][52];
    __shared__ float hidL[2][4][128];
    int l = blockIdx.y;
    int tid = threadIdx.x;
    int g = tid >> 7, c = tid & 127;
    const float* W1l = W1 + (size_t)l * NRBF * NHF;
    const float* W2l = W2 + (size_t)l * NHF * NHF;
    int t0 = blockIdx.x * 8 + g * 4;
    const float coeff = -0.5f / (STEP_F * STEP_F);
    const float dr = CUTOFF_F / (float)TBL;
    if (c < NRBF){
        float off = c * STEP_F;
        #pragma unroll
        for (int i = 0; i < 4; i++){
            int t = t0 + i; if (t > TBL) t = TBL;
            float d = t * dr - off;
            rbfL[g][i][c] = expf(coeff * d * d);
        }
    }
    __syncthreads();
    float acc[4];
    float bc = b1[l * NHF + c];
    #pragma unroll
    for (int i = 0; i < 4; i++) acc[i] = bc;
    for (int j = 0; j < NRBF; j++){
        float wv = W1l[j * NHF + c];
        #pragma unroll
        for (int i = 0; i < 4; i++) acc[i] = fmaf(rbfL[g][i][j], wv, acc[i]);
    }
    #pragma unroll
    for (int i = 0; i < 4; i++) hidL[g][i][c] = sspf(acc[i]);
    __syncthreads();
    float b2c = b2[l * NHF + c];
    #pragma unroll
    for (int i = 0; i < 4; i++) acc[i] = b2c;
    for (int j = 0; j < NHF; j++){
        float wv = W2l[j * NHF + c];
        #pragma unroll
        for (int i = 0; i < 4; i++) acc[i] = fmaf(hidL[g][i][j], wv, acc[i]);
    }
    #pragma unroll
    for (int i = 0; i < 4; i++){
        int t = t0 + i; if (t > TBL) t = TBL;
        float r = t * dr;
        float dc = (t >= TBL) ? 0.0f : 0.5f * (cosf(r * (PI_F / CUTOFF_F)) + 1.0f);
        float v = acc[i] * dc;
        Th[((size_t)l * TROWS + t) * NHF + c] = __builtin_bit_cast(unsigned short, (_Float16)v);
    }
}

// ---- MFMA fragment loads ----
// activations (B-operand): lane l -> atom row rfbase+(l&15), k-pairs ks*16+(l>>4)*4+{0..3}
static __device__ __forceinline__ fp16x8 ldX(const unsigned* A_u, int rfbase, int ks, int l){
    int row = rfbase + (l & 15);
    int wc = ks * 16 + ((l >> 4) << 2);
    uint4 v = *reinterpret_cast<const uint4*>(&A_u[row * 64 + (wc ^ ((row & 7) << 2))]);
    return __builtin_bit_cast(fp16x8, v);
}
// weights (A-operand): pre-packed fragment order
static __device__ __forceinline__ fp16x8 ldW(const uint4* __restrict__ Wp, int g, int ks, int cfg, int l){
    uint4 v = Wp[(((g << 2) + ks) * 8 + cfg) * 64 + l];
    return __builtin_bit_cast(fp16x8, v);
}

// D^T = W^T @ X^T: lane owns 4 consecutive channels of one atom -> no cross-lane epilogue.
// EPI 0: D -> dst.  EPI 1: ssp(D + bias) -> dst.  EPI 2: hreg += D + bias; -> dst
template<int EPI>
static __device__ __forceinline__ void gemm_phase(const uint4* __restrict__ Wp, int g,
                                                  const unsigned* A_u, uint2* D2,
                                                  float hreg[2][2][4], const float* __restrict__ bias,
                                                  int w, int l){
    f32x4 acc00 = {0,0,0,0}, acc01 = {0,0,0,0}, acc10 = {0,0,0,0}, acc11 = {0,0,0,0};
    #pragma unroll
    for (int ks = 0; ks < 4; ks++){
        fp16x8 wa0 = ldW(Wp, g, ks, w * 2 + 0, l);
        fp16x8 wa1 = ldW(Wp, g, ks, w * 2 + 1, l);
        fp16x8 xb0 = ldX(A_u, 0, ks, l);
        fp16x8 xb1 = ldX(A_u, 16, ks, l);
        acc00 = __builtin_amdgcn_mfma_f32_16x16x32_f16(wa0, xb0, acc00, 0, 0, 0);
        acc01 = __builtin_amdgcn_mfma_f32_16x16x32_f16(wa0, xb1, acc01, 0, 0, 0);
        acc10 = __builtin_amdgcn_mfma_f32_16x16x32_f16(wa1, xb0, acc10, 0, 0, 0);
        acc11 = __builtin_amdgcn_mfma_f32_16x16x32_f16(wa1, xb1, acc11, 0, 0, 0);
    }
    #pragma unroll
    for (int chf = 0; chf < 2; chf++){
        int ch0 = (w * 2 + chf) * 16 + ((l >> 4) << 2);
        float4 bv = {0,0,0,0};
        if (EPI >= 1) bv = ld4(bias + ch0);
        #pragma unroll
        for (int af = 0; af < 2; af++){
            f32x4 a = (chf == 0) ? (af == 0 ? acc00 : acc01) : (af == 0 ? acc10 : acc11);
            int atom = af * 16 + (l & 15);
            float v0 = a[0] + bv.x, v1 = a[1] + bv.y, v2 = a[2] + bv.z, v3 = a[3] + bv.w;
            if (EPI == 1){ v0 = sspf(v0); v1 = sspf(v1); v2 = sspf(v2); v3 = sspf(v3); }
            if (EPI == 2){
                v0 += hreg[chf][af][0]; hreg[chf][af][0] = v0;
                v1 += hreg[chf][af][1]; hreg[chf][af][1] = v1;
                v2 += hreg[chf][af][2]; hreg[chf][af][2] = v2;
                v3 += hreg[chf][af][3]; hreg[chf][af][3] = v3;
            }
            D2[(atom << 5) + (((ch0 >> 2) ^ ((atom & 7) << 1)))] = make_uint2(packh(v0, v1), packh(v2, v3));
        }
    }
}

// ---- mega kernel: one block = one molecule, all 3 layers + readout ----
__global__ __launch_bounds__(256, 4) void k_mega(const int* __restrict__ z, const float* __restrict__ coord,
                                                 const float* __restrict__ emask, const float* __restrict__ amask,
                                                 const float* __restrict__ emb,
                                                 const uint4* __restrict__ Wp,
                                                 const float* __restrict__ o_b1, const float* __restrict__ o_b2,
                                                 const unsigned* __restrict__ Tb,
                                                 const float* __restrict__ dW1, const float* __restrict__ db1,
                                                 const float* __restrict__ dW2, const float* __restrict__ db2,
                                                 const int* __restrict__ ridx, const float* __restrict__ rsign,
                                                 float* __restrict__ pred, int nn){
    __shared__ __align__(16) unsigned hbf[32 * 64];     // f16 h (X input)
    __shared__ __align__(16) unsigned xfb[32 * 64];     // xf / t (f16)
    __shared__ __align__(16) unsigned mbu[32 * 64];     // edge messages m (f16)
    __shared__ int      pkE[32 * 32];                   // (t<<8) | col
    __shared__ int      cntL[32];
    __shared__ int      cntP[16];
    __shared__ int      zL[32];
    __shared__ unsigned maskL[32];
    __shared__ float    cxyz[96];
    __shared__ float    amL[32];
    __shared__ float    hsb[NHF];

    int mol = blockIdx.x;
    int tid = threadIdx.x;
    int w = tid >> 6, l = tid & 63;
    int molA = mol * nn;
    int km = nn - 1;
    int ne = nn * km;

    uint2* hbf2 = reinterpret_cast<uint2*>(hbf);
    uint2* xfb2 = reinterpret_cast<uint2*>(xfb);
    uint2* mbu2 = reinterpret_cast<uint2*>(mbu);

    // ---- cooperative staging ----
    if (tid < 32){ maskL[tid] = 0u; cntL[tid] = 0; }
    if (tid < 3 * nn) cxyz[tid] = coord[(size_t)molA * 3 + tid];
    if (tid < 32)     amL[tid] = (tid < nn) ? amask[molA + tid] : 0.0f;
    if (tid < 32)     zL[tid]  = (tid < nn) ? z[molA + tid] : 0;
    __syncthreads();
    for (int e = tid; e < ne; e += 256){
        if (emask[(size_t)molA * km + e] != 0.0f){
            int a = e / km, k = e - a * km;
            atomicOr(&maskL[a], 1u << k);
        }
    }

    // ---- h init: registers [chf][af][r] (ch-major C-layout) + f16 LDS copy ----
    float hreg[2][2][4];
    #pragma unroll
    for (int chf = 0; chf < 2; chf++){
        int ch0 = (w * 2 + chf) * 16 + ((l >> 4) << 2);
        #pragma unroll
        for (int af = 0; af < 2; af++){
            int atom = af * 16 + (l & 15);
            float4 v = {0,0,0,0};
            if (atom < nn) v = ld4(emb + (size_t)zL[atom] * NHF + ch0);
            hreg[chf][af][0] = v.x; hreg[chf][af][1] = v.y;
            hreg[chf][af][2] = v.z; hreg[chf][af][3] = v.w;
            hbf2[(atom << 5) + (((ch0 >> 2) ^ ((atom & 7) << 1)))] = make_uint2(packh(v.x, v.y), packh(v.z, v.w));
        }
    }
    __syncthreads();

    // ---- per-atom active-edge lists ----
    if (tid < nn){
        int ai = tid;
        unsigned msk = maskL[ai];
        float ax = cxyz[ai*3], ay = cxyz[ai*3+1], az = cxyz[ai*3+2];
        int cnt = 0;
        for (int k = 0; k < km; k++){
            int nb = k + (k >= ai ? 1 : 0);
            float dx = ax - cxyz[nb*3], dy = ay - cxyz[nb*3+1], dz = az - cxyz[nb*3+2];
            float r = sqrtf(dx*dx + dy*dy + dz*dz);
            int t = (int)(r * TINV + 0.5f);
            if (((msk >> k) & 1u) && t < TBL){
                pkE[ai * 32 + cnt] = nb | (t << 8);
                cnt++;
            }
        }
        cntL[ai] = cnt;
    }
    __syncthreads();
    // pad each atom's list to pair-max (multiple of 4); dummy -> T row TBL (zeros)
    if (tid < 32){
        int mycnt = cntL[tid];
        int ocnt  = cntL[tid ^ 1];
        int mx = ((mycnt > ocnt ? mycnt : ocnt) + 3) & ~3;
        for (int k = mycnt; k < mx; k++) pkE[tid * 32 + k] = (TBL << 8);
        if (!(tid & 1)) cntP[tid >> 1] = mx;
    }
    __syncthreads();

    int h2 = l >> 5;            // atom-in-pair selector
    int l5 = l & 31;
    for (int L = 0; L < LAYERS; L++){
        // in2f: xf = h @ W (no bias)
        gemm_phase<0>(Wp, L * 3 + 0, hbf, xfb2, hreg, o_b1, w, l);
        __syncthreads();
        // edge messages: m[a] = sum_k xf[col_k] * T[t_k]; 2 atoms/wave, 4 ch/lane
        const char* TlB = (const char*)(Tb + (size_t)L * TROWS * 64);
        for (int pr = w; pr < 16; pr += 4){
            int a0 = 2 * pr + h2;
            int cnt = cntP[pr];
            const int* pe = &pkE[a0 * 32];
            f16x2 acc0; acc0[0] = (_Float16)0; acc0[1] = (_Float16)0;
            f16x2 acc1 = acc0;
            for (int k = 0; k < cnt; k += 4){
                #pragma unroll
                for (int j = 0; j < 4; j++){
                    int p = pe[k + j];
                    uint2 tw = *reinterpret_cast<const uint2*>(TlB + (p & ~0xFF) + (l5 << 3));
                    int atom = p & 31;
                    uint2 xw = xfb2[(atom << 5) + (l5 ^ ((atom & 7) << 1))];
                    f16x2 t0 = __builtin_bit_cast(f16x2, tw.x);
                    f16x2 t1 = __builtin_bit_cast(f16x2, tw.y);
                    f16x2 x0 = __builtin_bit_cast(f16x2, xw.x);
                    f16x2 x1 = __builtin_bit_cast(f16x2, xw.y);
                    acc0 = t0 * x0 + acc0;
                    acc1 = t1 * x1 + acc1;
                }
            }
            mbu2[(a0 << 5) + (l5 ^ ((a0 & 7) << 1))] =
                make_uint2(__builtin_bit_cast(unsigned, acc0), __builtin_bit_cast(unsigned, acc1));
        }
        __syncthreads();
        // o1: t = ssp(m @ W + b1)
        gemm_phase<1>(Wp, L * 3 + 1, mbu, xfb2, hreg, o_b1 + L * NHF, w, l);
        __syncthreads();
        // o2: h(reg) += t @ W + b2 ; refresh h f16 copy
        gemm_phase<2>(Wp, L * 3 + 2, xfb, hbf2, hreg, o_b2 + L * NHF, w, l);
        __syncthreads();
    }

    // ---- readout: sum over atoms (cross-lane over l&15) + decoder + scatter ----
    {
        float s[2][4];
        #pragma unroll
        for (int chf = 0; chf < 2; chf++)
            #pragma unroll
            for (int r = 0; r < 4; r++)
                s[chf][r] = hreg[chf][0][r] * amL[l & 15] + hreg[chf][1][r] * amL[16 + (l & 15)];
        #pragma unroll
        for (int o = 1; o < 16; o <<= 1){
            #pragma unroll
            for (int chf = 0; chf < 2; chf++)
                #pragma unroll
                for (int r = 0; r < 4; r++)
                    s[chf][r] += __shfl_xor(s[chf][r], o);
        }
        if (!(l & 15)){
            #pragma unroll
            for (int chf = 0; chf < 2; chf++)
                #pragma unroll
                for (int r = 0; r < 4; r++)
                    hsb[(w * 2 + chf) * 16 + ((l >> 4) << 2) + r] = s[chf][r];
        }
    }
    __syncthreads();
    // decoder: 256 threads = 64 outputs x 4 c-partitions, reduce in LDS (reuse pkE)
    {
        float* red = (float*)pkE;
        int o = tid & 63, part = tid >> 6;
        float u = 0.0f;
        #pragma unroll 8
        for (int c = part * 32; c < part * 32 + 32; c++)
            u = fmaf(hsb[c], dW1[c * 64 + o], u);
        red[part * 64 + o] = u;
    }
    __syncthreads();
    if (tid < 64){
        float u = ((float*)pkE)[tid] + ((float*)pkE)[64 + tid] + ((float*)pkE)[128 + tid]
                + ((float*)pkE)[192 + tid] + db1[tid];
        float p = sspf(u) * dW2[tid];
        #pragma unroll
        for (int o = 32; o > 0; o >>= 1) p += __shfl_down(p, o);
        if (tid == 0) atomicAdd(&pred[ridx[mol]], (p + db2[0]) * rsign[mol]);
    }
}

extern "C" void kernel_launch(void* const* d_in, const int* in_sizes, int n_in,
                              void* d_out, int out_size, void* d_ws, size_t ws_size,
                              hipStream_t stream){
    const int*   z      = (const int*)  d_in[0];
    const float* coord  = (const float*)d_in[1];
    const float* amask  = (const float*)d_in[3];
    const float* emask  = (const float*)d_in[4];
    const int*   ridx   = (const int*)  d_in[5];
    const float* rsign  = (const float*)d_in[6];
    const float* emb    = (const float*)d_in[7];
    const float* in2f_W = (const float*)d_in[10];
    const float* f_W1   = (const float*)d_in[11];
    const float* f_b1   = (const float*)d_in[12];
    const float* f_W2   = (const float*)d_in[13];
    const float* f_b2   = (const float*)d_in[14];
    const float* o_W1   = (const float*)d_in[15];
    const float* o_b1   = (const float*)d_in[16];
    const float* o_W2   = (const float*)d_in[17];
    const float* o_b2   = (const float*)d_in[18];
    const float* dW1    = (const float*)d_in[19];
    const float* db1    = (const float*)d_in[20];
    const float* dW2    = (const float*)d_in[21];
    const float* db2    = (const float*)d_in[22];

    const int N  = in_sizes[0];
    const int B  = in_sizes[5];
    const int nn = N / B;
    (void)n_in; (void)ws_size;

    // workspace carve
    uint4*    Wp = (uint4*)d_ws;                                   // 9*2048*16 B
    unsigned* Tb = (unsigned*)((char*)d_ws + 9 * 2048 * 16);       // LAYERS*TROWS*64 words (f16 pairs)

    (void)hipMemsetAsync(d_out, 0, (size_t)out_size * sizeof(float), stream);
    k_pack <<<72, 256, 0, stream>>>(in2f_W, o_W1, o_W2, Wp);
    k_table<<<dim3((TROWS + 7) / 8, LAYERS), 256, 0, stream>>>(f_W1, f_b1, f_W2, f_b2,
                                                               (unsigned short*)Tb);
    k_mega <<<B, 256, 0, stream>>>(z, coord, emask, amask, emb, Wp, o_b1, o_b2, Tb,
                                   dW1, db1, dW2, db2, ridx, rsign, (float*)d_out, nn);
}